// Round 1
// baseline (694.553 us; speedup 1.0000x reference)
//
#include <hip/hip_runtime.h>
#include <math.h>

#define Bb 64
#define Ss 512
#define Tt 32
#define H2 1024   // hidden*2 (= feature dim of h)
#define FF 2048   // 2*H2 (w1_w row stride)
#define ATT 512
#define MM (Bb * Ss)   // 32768 rows in the main GEMM

#define BM 128
#define BN 128
#define BK 32

// ---------------------------------------------------------------- init
__global__ void init_kernel(float* __restrict__ beta, float* __restrict__ out) {
    int i = blockIdx.x * 256 + threadIdx.x;
    if (i < Bb * Ss) beta[i] = 0.0f;
    if (i < Bb * H2) out[i] = 0.0f;
}

// ---------------------------------------------------------------- ht mean over T
__global__ void mean_kernel(const float* __restrict__ ht, float* __restrict__ ht_mean) {
    int b = blockIdx.x;
    int d4 = threadIdx.x;                      // 256 threads x float4 = 1024 dims
    const float4* p = (const float4*)(ht + (size_t)b * Tt * H2);
    float4 acc = make_float4(0.f, 0.f, 0.f, 0.f);
    #pragma unroll 4
    for (int t = 0; t < Tt; ++t) {
        float4 v = p[(size_t)t * (H2 / 4) + d4];
        acc.x += v.x; acc.y += v.y; acc.z += v.z; acc.w += v.w;
    }
    const float inv = 1.0f / (float)Tt;
    acc.x *= inv; acc.y *= inv; acc.z *= inv; acc.w *= inv;
    ((float4*)(ht_mean + (size_t)b * H2))[d4] = acc;
}

// ---------------------------------------------------------------- c2[b,att] = ht_mean[b] . w1_w[att, 1024:2048] + w1_b[att]
__global__ void c2_kernel(const float* __restrict__ ht_mean, const float* __restrict__ w1_w,
                          const float* __restrict__ w1_b, float* __restrict__ c2) {
    __shared__ float hm[H2];
    int b = blockIdx.x;
    for (int i = threadIdx.x; i < H2; i += 256) hm[i] = ht_mean[(size_t)b * H2 + i];
    __syncthreads();
    for (int a = threadIdx.x; a < ATT; a += 256) {
        const float4* w = (const float4*)(w1_w + (size_t)a * FF + H2);
        float acc = 0.f;
        #pragma unroll 4
        for (int k4 = 0; k4 < H2 / 4; ++k4) {
            float4 wv = w[k4];
            acc += wv.x * hm[k4 * 4 + 0] + wv.y * hm[k4 * 4 + 1]
                 + wv.z * hm[k4 * 4 + 2] + wv.w * hm[k4 * 4 + 3];
        }
        c2[(size_t)b * ATT + a] = acc + w1_b[a];
    }
}

// ---------------------------------------------------------------- main GEMM (fp32 vector ALU) + tanh + u dot -> beta (fused)
// M=32768 (b*s), N=512 (att), K=1024. A = h, B = w1_w[:, :1024] (row-major, stride 2048).
__global__ __launch_bounds__(256) void gemm_beta_kernel(
        const float* __restrict__ h, const float* __restrict__ w1_w,
        const float* __restrict__ c2, const float* __restrict__ u_w,
        float* __restrict__ beta) {
    __shared__ float As[BK][BM];   // transposed tiles: [k][m], 16 KB
    __shared__ float Bs[BK][BN];   // [k][n], 16 KB

    const int m0 = blockIdx.x * BM;
    const int n0 = blockIdx.y * BN;
    const int tid = (int)threadIdx.x;
    const int lrow = tid & 31;     // staging: row-within-32
    const int kq   = tid >> 5;     // staging: which float4 of the 32-wide k strip (0..7)
    const int tx = tid & 15;       // compute: n-group
    const int ty = tid >> 4;       // compute: m-group

    float acc[8][8] = {};

    const float* Ag = h    + (size_t)(m0 + lrow) * H2 + kq * 4;
    const float* Bg = w1_w + (size_t)(n0 + lrow) * FF + kq * 4;

    for (int k0 = 0; k0 < H2; k0 += BK) {
        // ---- stage A,B tiles into LDS (transposed). 2-way-max bank aliasing on stores.
        #pragma unroll
        for (int p = 0; p < 4; ++p) {
            float4 av = *(const float4*)(Ag + (size_t)(p * 32) * H2 + k0);
            float4 bv = *(const float4*)(Bg + (size_t)(p * 32) * FF + k0);
            int r = lrow + p * 32;
            int kk = kq * 4;
            As[kk + 0][r] = av.x; As[kk + 1][r] = av.y; As[kk + 2][r] = av.z; As[kk + 3][r] = av.w;
            Bs[kk + 0][r] = bv.x; Bs[kk + 1][r] = bv.y; Bs[kk + 2][r] = bv.z; Bs[kk + 3][r] = bv.w;
        }
        __syncthreads();
        // ---- compute: 8x8 per thread, 64 FMA per k vs 4 ds_read_b128 -> VALU-bound
        #pragma unroll
        for (int k = 0; k < BK; ++k) {
            float4 a0 = *(const float4*)&As[k][ty * 8];
            float4 a1 = *(const float4*)&As[k][ty * 8 + 4];
            float4 b0 = *(const float4*)&Bs[k][tx * 8];
            float4 b1 = *(const float4*)&Bs[k][tx * 8 + 4];
            float av[8] = {a0.x, a0.y, a0.z, a0.w, a1.x, a1.y, a1.z, a1.w};
            float bv[8] = {b0.x, b0.y, b0.z, b0.w, b1.x, b1.y, b1.z, b1.w};
            #pragma unroll
            for (int i = 0; i < 8; ++i)
                #pragma unroll
                for (int j = 0; j < 8; ++j)
                    acc[i][j] = fmaf(av[i], bv[j], acc[i][j]);
        }
        __syncthreads();
    }

    // ---- fused epilogue: a = tanh(acc + c2[b,n]); beta_partial = a . u_w
    const int b_idx = m0 / Ss;     // BM=128 divides S=512 -> whole block is one batch
    float rowp[8] = {};
    #pragma unroll
    for (int j = 0; j < 8; ++j) {
        int n = n0 + tx * 8 + j;
        float c2v = c2[(size_t)b_idx * ATT + n];
        float uv  = u_w[n];
        #pragma unroll
        for (int i = 0; i < 8; ++i) {
            float a_val = tanhf(acc[i][j] + c2v);
            rowp[i] = fmaf(a_val, uv, rowp[i]);
        }
    }
    // rows owned by ty are disjoint per wave (wave = 4 consecutive ty); reduce across tx (16 lanes)
    #pragma unroll
    for (int i = 0; i < 8; ++i) {
        float v = rowp[i];
        v += __shfl_xor(v, 8, 16);
        v += __shfl_xor(v, 4, 16);
        v += __shfl_xor(v, 2, 16);
        v += __shfl_xor(v, 1, 16);
        if (tx == 0) atomicAdd(&beta[(size_t)m0 + ty * 8 + i], v);
    }
}

// ---------------------------------------------------------------- masked softmax over S per batch
__global__ void softmax_kernel(const float* __restrict__ beta, const int* __restrict__ h_mask,
                               float* __restrict__ alpha) {
    __shared__ float red[16];
    int b = blockIdx.x;
    int s = (int)threadIdx.x;   // 512 threads
    float v = (h_mask[(size_t)b * Ss + s] != 0) ? beta[(size_t)b * Ss + s] : -1e20f;

    float m = v;
    #pragma unroll
    for (int off = 32; off >= 1; off >>= 1) m = fmaxf(m, __shfl_xor(m, off, 64));
    int wave = s >> 6;
    if ((s & 63) == 0) red[wave] = m;
    __syncthreads();
    float mx = red[0];
    #pragma unroll
    for (int w = 1; w < 8; ++w) mx = fmaxf(mx, red[w]);

    float e = expf(v - mx);
    float sum = e;
    #pragma unroll
    for (int off = 32; off >= 1; off >>= 1) sum += __shfl_xor(sum, off, 64);
    __syncthreads();
    if ((s & 63) == 0) red[8 + wave] = sum;
    __syncthreads();
    float tot = 0.f;
    #pragma unroll
    for (int w = 0; w < 8; ++w) tot += red[8 + w];

    alpha[(size_t)b * Ss + s] = e / tot;
}

// ---------------------------------------------------------------- s[b,d] = sum_s alpha[b,s] * h[b,s,d]
__global__ void wsum_kernel(const float* __restrict__ h, const float* __restrict__ alpha,
                            float* __restrict__ out) {
    int b = blockIdx.x;
    int d = blockIdx.y * 256 + (int)threadIdx.x;   // 4 chunks of 256 dims
    int s0 = blockIdx.z * 128;                     // 4 s-chunks
    const float* hp = h + (size_t)b * Ss * H2 + (size_t)s0 * H2 + d;
    const float* ap = alpha + (size_t)b * Ss + s0;
    float acc = 0.f;
    #pragma unroll 4
    for (int s = 0; s < 128; ++s) acc = fmaf(ap[s], hp[(size_t)s * H2], acc);
    atomicAdd(&out[(size_t)b * H2 + d], acc);
}

// ---------------------------------------------------------------- launch
extern "C" void kernel_launch(void* const* d_in, const int* in_sizes, int n_in,
                              void* d_out, int out_size, void* d_ws, size_t ws_size,
                              hipStream_t stream) {
    const float* h      = (const float*)d_in[0];
    const int*   h_mask = (const int*)d_in[1];
    const float* ht     = (const float*)d_in[2];
    const float* w1_w   = (const float*)d_in[3];
    const float* w1_b   = (const float*)d_in[4];
    const float* u_w    = (const float*)d_in[5];
    float* out = (float*)d_out;

    float* ws      = (float*)d_ws;
    float* ht_mean = ws;                 // 65536 floats
    float* c2      = ws + 65536;         // 32768
    float* beta    = ws + 98304;         // 32768
    float* alpha   = ws + 131072;        // 32768  (total 640 KB)

    hipLaunchKernelGGL(init_kernel, dim3(256), dim3(256), 0, stream, beta, out);
    hipLaunchKernelGGL(mean_kernel, dim3(Bb), dim3(256), 0, stream, ht, ht_mean);
    hipLaunchKernelGGL(c2_kernel, dim3(Bb), dim3(256), 0, stream, ht_mean, w1_w, w1_b, c2);
    hipLaunchKernelGGL(gemm_beta_kernel, dim3(MM / BM, ATT / BN), dim3(256), 0, stream,
                       h, w1_w, c2, u_w, beta);
    hipLaunchKernelGGL(softmax_kernel, dim3(Bb), dim3(512), 0, stream, beta, h_mask, alpha);
    hipLaunchKernelGGL(wsum_kernel, dim3(Bb, H2 / 256, 4), dim3(256), 0, stream, h, alpha, out);
}

// Round 2
// 323.239 us; speedup vs baseline: 2.1487x; 2.1487x over previous
//
#include <hip/hip_runtime.h>
#include <math.h>
#include <stdint.h>

#define Bb 64
#define Ss 512
#define Tt 32
#define H2 1024   // feature dim of h
#define FF 2048   // w1_w row stride
#define ATT 512
#define MM (Bb * Ss)

typedef short bf8 __attribute__((ext_vector_type(8)));   // 8 bf16 (guide §3 frag type)
typedef float f4 __attribute__((ext_vector_type(4)));

// fp32 -> bf16 (RNE), bit-level so we never depend on __bf16 type plumbing
__device__ __forceinline__ unsigned short f2bf(float f) {
    unsigned u = __float_as_uint(f);
    u = (u + 0x7fffu + ((u >> 16) & 1u)) >> 16;
    return (unsigned short)u;
}

__device__ __forceinline__ void gl_lds16(const void* g, void* l) {
    __builtin_amdgcn_global_load_lds((const __attribute__((address_space(1))) void*)g,
                                     (__attribute__((address_space(3))) void*)l, 16, 0, 0);
}

// ---------------------------------------------------------------- init
__global__ void init_kernel(float* __restrict__ beta, float* __restrict__ out) {
    int i = blockIdx.x * 256 + threadIdx.x;
    if (i < Bb * Ss) beta[i] = 0.0f;
    if (i < Bb * H2) out[i] = 0.0f;
}

// ---------------------------------------------------------------- ht mean over T
__global__ void mean_kernel(const float* __restrict__ ht, float* __restrict__ ht_mean) {
    int b = blockIdx.x;
    int d4 = threadIdx.x;
    const float4* p = (const float4*)(ht + (size_t)b * Tt * H2);
    float4 acc = make_float4(0.f, 0.f, 0.f, 0.f);
    #pragma unroll 4
    for (int t = 0; t < Tt; ++t) {
        float4 v = p[(size_t)t * (H2 / 4) + d4];
        acc.x += v.x; acc.y += v.y; acc.z += v.z; acc.w += v.w;
    }
    const float inv = 1.0f / (float)Tt;
    acc.x *= inv; acc.y *= inv; acc.z *= inv; acc.w *= inv;
    ((float4*)(ht_mean + (size_t)b * H2))[d4] = acc;
}

// ---------------------------------------------------------------- c2[b,a] = ht_mean[b].w1_w[a,1024:2048] + w1_b[a]
// grid (Bb, 8): 64 atts per block, 4 threads per att (256-length partials) -> 512 blocks
__global__ __launch_bounds__(256) void c2_kernel2(const float* __restrict__ ht_mean,
                                                  const float* __restrict__ w1_w,
                                                  const float* __restrict__ w1_b,
                                                  float* __restrict__ c2) {
    __shared__ float hm[H2];
    int b = blockIdx.x;
    for (int i = threadIdx.x; i < H2; i += 256) hm[i] = ht_mean[(size_t)b * H2 + i];
    __syncthreads();
    int a = blockIdx.y * 64 + ((int)threadIdx.x >> 2);
    int q = (int)threadIdx.x & 3;
    const float4* w   = (const float4*)(w1_w + (size_t)a * FF + H2 + q * 256);
    const float4* hm4 = (const float4*)(hm + q * 256);
    float acc = 0.f;
    #pragma unroll 8
    for (int k = 0; k < 64; ++k) {
        float4 wv = w[k]; float4 hv = hm4[k];
        acc += wv.x * hv.x + wv.y * hv.y + wv.z * hv.z + wv.w * hv.w;
    }
    acc += __shfl_xor(acc, 1);
    acc += __shfl_xor(acc, 2);
    if (q == 0) c2[(size_t)b * ATT + a] = acc + w1_b[a];
}

// ---------------------------------------------------------------- fp32 -> bf16 converts
__global__ void convh_kernel(const float* __restrict__ in, unsigned short* __restrict__ out) {
    size_t i = ((size_t)blockIdx.x * 256 + threadIdx.x) * 8;
    float4 a = *(const float4*)(in + i);
    float4 b = *(const float4*)(in + i + 4);
    bf8 v = { (short)f2bf(a.x), (short)f2bf(a.y), (short)f2bf(a.z), (short)f2bf(a.w),
              (short)f2bf(b.x), (short)f2bf(b.y), (short)f2bf(b.z), (short)f2bf(b.w) };
    *(bf8*)(out + i) = v;
}

// w1a_bf[a][k] = bf16(w1_w[a][k]), k<1024 (strided source rows)
__global__ void convw_kernel(const float* __restrict__ w1_w, unsigned short* __restrict__ out) {
    size_t e = ((size_t)blockIdx.x * 256 + threadIdx.x) * 8;
    int row = (int)(e >> 10);
    int c = (int)(e & 1023);
    const float* src = w1_w + (size_t)row * FF + c;
    float4 a = *(const float4*)(src);
    float4 b = *(const float4*)(src + 4);
    bf8 v = { (short)f2bf(a.x), (short)f2bf(a.y), (short)f2bf(a.z), (short)f2bf(a.w),
              (short)f2bf(b.x), (short)f2bf(b.y), (short)f2bf(b.z), (short)f2bf(b.w) };
    *(bf8*)(out + e) = v;
}

// ---------------------------------------------------------------- MFMA GEMM + fused tanh/u epilogue -> beta
// M=32768, N=512, K=1024. 128x128 tile, BK=32, 4 waves (2x2), 16x16x32 bf16 MFMA (m97 structure).
__global__ __launch_bounds__(256) void gemm_mfma_kernel(
        const unsigned short* __restrict__ hb, const unsigned short* __restrict__ wb,
        const float* __restrict__ c2, const float* __restrict__ u_w,
        float* __restrict__ beta) {
    __shared__ __align__(16) unsigned short As[128][32];   // 8KB, [m][k]
    __shared__ __align__(16) unsigned short Bs[128][32];   // 8KB, [n][k]

    const int tid = (int)threadIdx.x;
    const int m0 = blockIdx.x * 128;
    const int n0 = blockIdx.y * 128;
    const int wid = tid >> 6, lane = tid & 63;
    const int wr = (wid >> 1) * 64;        // wave m offset within tile
    const int wc = (wid & 1) * 64;         // wave n offset within tile
    const int col = lane & 15, rg = lane >> 4;

    f4 acc[4][4] = {};

    // staging map: global row = tid>>2 (+64 on 2nd call), 8-elem chunk = (tid&3)*8
    const int srow = tid >> 2;
    const int skq = (tid & 3) * 8;
    const unsigned short* a0 = hb + (size_t)(m0 + srow) * H2 + skq;
    const unsigned short* b0 = wb + (size_t)(n0 + srow) * H2 + skq;
    // wave-uniform LDS bases; lane writes base + lane*16B (= linear [row][k] layout)
    unsigned short* lA = &As[0][0] + (size_t)wid * 512;
    unsigned short* lB = &Bs[0][0] + (size_t)wid * 512;

    for (int k0 = 0; k0 < H2; k0 += 32) {
        gl_lds16(a0 + k0, lA);
        gl_lds16(a0 + k0 + (size_t)64 * H2, lA + 2048);
        gl_lds16(b0 + k0, lB);
        gl_lds16(b0 + k0 + (size_t)64 * H2, lB + 2048);
        __syncthreads();   // drains vmcnt before reads
        bf8 av[4], bv[4];
        #pragma unroll
        for (int i = 0; i < 4; ++i) {
            av[i] = *(const bf8*)&As[wr + i * 16 + col][rg * 8];
            bv[i] = *(const bf8*)&Bs[wc + i * 16 + col][rg * 8];
        }
        #pragma unroll
        for (int i = 0; i < 4; ++i)
            #pragma unroll
            for (int j = 0; j < 4; ++j)
                acc[i][j] = __builtin_amdgcn_mfma_f32_16x16x32_bf16(av[i], bv[j], acc[i][j], 0, 0, 0);
        __syncthreads();   // before next-tile overwrite
    }

    // epilogue: beta[m] += sum_n tanh(acc + c2[b,n]) * u[n]
    const int b_idx = blockIdx.x >> 2;     // BM=128 divides S=512
    const float* c2b = c2 + (size_t)b_idx * ATT + n0 + wc;
    const float* ub = u_w + n0 + wc;
    #pragma unroll
    for (int i = 0; i < 4; ++i) {
        float rp[4] = {0.f, 0.f, 0.f, 0.f};
        #pragma unroll
        for (int j = 0; j < 4; ++j) {
            int n = j * 16 + col;
            float cv = c2b[n];
            float uv = ub[n];
            #pragma unroll
            for (int r = 0; r < 4; ++r)
                rp[r] += tanhf(acc[i][j][r] + cv) * uv;
        }
        #pragma unroll
        for (int r = 0; r < 4; ++r) {
            float v = rp[r];
            v += __shfl_xor(v, 1);
            v += __shfl_xor(v, 2);
            v += __shfl_xor(v, 4);
            v += __shfl_xor(v, 8);
            if (col == 0)
                atomicAdd(&beta[(size_t)m0 + wr + i * 16 + rg * 4 + r], v);
        }
    }
}

// ---------------------------------------------------------------- fallback fp32 GEMM (round-1 validated)
__global__ __launch_bounds__(256) void gemm_beta_kernel(
        const float* __restrict__ h, const float* __restrict__ w1_w,
        const float* __restrict__ c2, const float* __restrict__ u_w,
        float* __restrict__ beta) {
    __shared__ float As[32][128];
    __shared__ float Bs[32][128];
    const int m0 = blockIdx.x * 128;
    const int n0 = blockIdx.y * 128;
    const int tid = (int)threadIdx.x;
    const int lrow = tid & 31;
    const int kq = tid >> 5;
    const int tx = tid & 15;
    const int ty = tid >> 4;
    float acc[8][8] = {};
    const float* Ag = h + (size_t)(m0 + lrow) * H2 + kq * 4;
    const float* Bg = w1_w + (size_t)(n0 + lrow) * FF + kq * 4;
    for (int k0 = 0; k0 < H2; k0 += 32) {
        #pragma unroll
        for (int p = 0; p < 4; ++p) {
            float4 av = *(const float4*)(Ag + (size_t)(p * 32) * H2 + k0);
            float4 bv = *(const float4*)(Bg + (size_t)(p * 32) * FF + k0);
            int r = lrow + p * 32;
            int kk = kq * 4;
            As[kk + 0][r] = av.x; As[kk + 1][r] = av.y; As[kk + 2][r] = av.z; As[kk + 3][r] = av.w;
            Bs[kk + 0][r] = bv.x; Bs[kk + 1][r] = bv.y; Bs[kk + 2][r] = bv.z; Bs[kk + 3][r] = bv.w;
        }
        __syncthreads();
        #pragma unroll
        for (int k = 0; k < 32; ++k) {
            float4 a0 = *(const float4*)&As[k][ty * 8];
            float4 a1 = *(const float4*)&As[k][ty * 8 + 4];
            float4 b0 = *(const float4*)&Bs[k][tx * 8];
            float4 b1 = *(const float4*)&Bs[k][tx * 8 + 4];
            float av[8] = {a0.x, a0.y, a0.z, a0.w, a1.x, a1.y, a1.z, a1.w};
            float bv[8] = {b0.x, b0.y, b0.z, b0.w, b1.x, b1.y, b1.z, b1.w};
            #pragma unroll
            for (int i = 0; i < 8; ++i)
                #pragma unroll
                for (int j = 0; j < 8; ++j)
                    acc[i][j] = fmaf(av[i], bv[j], acc[i][j]);
        }
        __syncthreads();
    }
    const int b_idx = m0 / Ss;
    float rowp[8] = {};
    #pragma unroll
    for (int j = 0; j < 8; ++j) {
        int n = n0 + tx * 8 + j;
        float c2v = c2[(size_t)b_idx * ATT + n];
        float uv = u_w[n];
        #pragma unroll
        for (int i = 0; i < 8; ++i)
            rowp[i] = fmaf(tanhf(acc[i][j] + c2v), uv, rowp[i]);
    }
    #pragma unroll
    for (int i = 0; i < 8; ++i) {
        float v = rowp[i];
        v += __shfl_xor(v, 8, 16);
        v += __shfl_xor(v, 4, 16);
        v += __shfl_xor(v, 2, 16);
        v += __shfl_xor(v, 1, 16);
        if (tx == 0) atomicAdd(&beta[(size_t)m0 + ty * 8 + i], v);
    }
}

// ---------------------------------------------------------------- masked softmax over S
__global__ void softmax_kernel(const float* __restrict__ beta, const int* __restrict__ h_mask,
                               float* __restrict__ alpha) {
    __shared__ float red[16];
    int b = blockIdx.x;
    int s = (int)threadIdx.x;
    float v = (h_mask[(size_t)b * Ss + s] != 0) ? beta[(size_t)b * Ss + s] : -1e20f;
    float m = v;
    #pragma unroll
    for (int off = 32; off >= 1; off >>= 1) m = fmaxf(m, __shfl_xor(m, off, 64));
    int wave = s >> 6;
    if ((s & 63) == 0) red[wave] = m;
    __syncthreads();
    float mx = red[0];
    #pragma unroll
    for (int w = 1; w < 8; ++w) mx = fmaxf(mx, red[w]);
    float e = expf(v - mx);
    float sum = e;
    #pragma unroll
    for (int off = 32; off >= 1; off >>= 1) sum += __shfl_xor(sum, off, 64);
    __syncthreads();
    if ((s & 63) == 0) red[8 + wave] = sum;
    __syncthreads();
    float tot = 0.f;
    #pragma unroll
    for (int w = 0; w < 8; ++w) tot += red[8 + w];
    alpha[(size_t)b * Ss + s] = e / tot;
}

// ---------------------------------------------------------------- s[b,d] = sum_s alpha[b,s] h[b,s,d]
__global__ void wsum_kernel(const float* __restrict__ h, const float* __restrict__ alpha,
                            float* __restrict__ out) {
    int b = blockIdx.x;
    int d = blockIdx.y * 256 + (int)threadIdx.x;
    int s0 = blockIdx.z * 128;
    const float* hp = h + (size_t)b * Ss * H2 + (size_t)s0 * H2 + d;
    const float* ap = alpha + (size_t)b * Ss + s0;
    float acc = 0.f;
    #pragma unroll 4
    for (int s = 0; s < 128; ++s) acc = fmaf(ap[s], hp[(size_t)s * H2], acc);
    atomicAdd(&out[(size_t)b * H2 + d], acc);
}

// ---------------------------------------------------------------- launch
extern "C" void kernel_launch(void* const* d_in, const int* in_sizes, int n_in,
                              void* d_out, int out_size, void* d_ws, size_t ws_size,
                              hipStream_t stream) {
    const float* h      = (const float*)d_in[0];
    const int*   h_mask = (const int*)d_in[1];
    const float* ht     = (const float*)d_in[2];
    const float* w1_w   = (const float*)d_in[3];
    const float* w1_b   = (const float*)d_in[4];
    const float* u_w    = (const float*)d_in[5];
    float* out = (float*)d_out;

    float* ws      = (float*)d_ws;
    float* ht_mean = ws;                 // 65536 floats
    float* c2      = ws + 65536;         // 32768
    float* beta    = ws + 98304;         // 32768
    float* alpha   = ws + 131072;        // 32768  -> 164864 floats = 659456 B
    unsigned short* w1a_bf = (unsigned short*)((char*)d_ws + 659456);            // 1 MB
    unsigned short* h_bf   = (unsigned short*)((char*)d_ws + 659456 + 1048576);  // 64 MB
    const size_t need = 659456 + 1048576 + (size_t)MM * H2 * 2;

    hipLaunchKernelGGL(init_kernel, dim3(256), dim3(256), 0, stream, beta, out);
    hipLaunchKernelGGL(mean_kernel, dim3(Bb), dim3(256), 0, stream, ht, ht_mean);
    hipLaunchKernelGGL(c2_kernel2, dim3(Bb, 8), dim3(256), 0, stream, ht_mean, w1_w, w1_b, c2);

    if (ws_size >= need) {
        hipLaunchKernelGGL(convw_kernel, dim3(256), dim3(256), 0, stream, w1_w, w1a_bf);
        hipLaunchKernelGGL(convh_kernel, dim3(16384), dim3(256), 0, stream, h, h_bf);
        hipLaunchKernelGGL(gemm_mfma_kernel, dim3(MM / 128, ATT / 128), dim3(256), 0, stream,
                           h_bf, w1a_bf, c2, u_w, beta);
    } else {
        hipLaunchKernelGGL(gemm_beta_kernel, dim3(MM / 128, ATT / 128), dim3(256), 0, stream,
                           h, w1_w, c2, u_w, beta);
    }

    hipLaunchKernelGGL(softmax_kernel, dim3(Bb), dim3(512), 0, stream, beta, h_mask, alpha);
    hipLaunchKernelGGL(wsum_kernel, dim3(Bb, H2 / 256, 4), dim3(256), 0, stream, h, alpha, out);
}